// Round 9
// baseline (346.201 us; speedup 1.0000x reference)
//
#include <hip/hip_runtime.h>
#include <cstdint>
#include <cstddef>

// Problem dims (B, D, F, T, H) = (256, 128, 8, 128, 128)
#define Bn 256
#define Dn 128
#define Fn 8
#define Tn 128
#define Hn 128
#define Kn 1024   // D*F
#define Mn 512    // 4*H

typedef float f32x4 __attribute__((ext_vector_type(4)));
typedef _Float16 h16x2 __attribute__((ext_vector_type(2)));
typedef _Float16 h16x4 __attribute__((ext_vector_type(4)));
typedef _Float16 h16x8 __attribute__((ext_vector_type(8)));

#if defined(__has_builtin)
#if __has_builtin(__builtin_amdgcn_cvt_pkrtz)
#define HAVE_PKRTZ 1
#else
#define HAVE_PKRTZ 0
#endif
#else
#define HAVE_PKRTZ 0
#endif

__device__ __forceinline__ uint32_t pack2_f16(float a, float b) {
#if HAVE_PKRTZ
  // builtin returns __fp16 ext_vector(2); union member must match exactly.
  typedef __fp16 fp16x2_t __attribute__((ext_vector_type(2)));
  union { fp16x2_t v; uint32_t u; } cv;
  cv.v = __builtin_amdgcn_cvt_pkrtz(a, b);
  return cv.u;
#else
  union { h16x2 h; uint32_t u; } cv;
  cv.h.x = (_Float16)a; cv.h.y = (_Float16)b;
  return cv.u;
#endif
}
__device__ __forceinline__ float sigm(float x) { return 1.0f / (1.0f + __expf(-x)); }
__device__ __forceinline__ float tanh_fast(float x) { return 1.0f - 2.0f / (__expf(2.0f * x) + 1.0f); }

// ---------------------------------------------------------------------------
// K1 (fused): blocks 0..8191   : ex[b,d] = input[b,d,:,:] . w_x
//             blocks 8192..8447: W_ih -> f16 MFMA A-frags
//             blocks 8448..8479: W_hh^T -> f16 MFMA B-frags (k_rec matvec)
// softmax shift-invariance kills the h/c/b_attn term entirely.
// ---------------------------------------------------------------------------
__global__ __launch_bounds__(256) void k_ex_prep(
    const float* __restrict__ input, const float* __restrict__ w_attn,
    const float* __restrict__ W_ih, const float* __restrict__ W_hh,
    float* __restrict__ ex, unsigned short* __restrict__ whf,
    unsigned short* __restrict__ whh) {
  __shared__ float wx[Kn];
  const int tid = threadIdx.x;
  if (blockIdx.x < 8192) {
    ((float4*)wx)[tid] = ((const float4*)(w_attn + 2 * Hn))[tid];
    __syncthreads();
    const int w = tid >> 6, lane = tid & 63;
    const int gid = blockIdx.x * 4 + w;  // b*128 + d
    const float4* xp = (const float4*)(input + (size_t)gid * Kn);
    const float4* wx4 = (const float4*)wx;
    float acc = 0.f;
#pragma unroll
    for (int r = 0; r < 4; ++r) {
      float4 x = xp[lane + r * 64];
      float4 ww = wx4[lane + r * 64];
      acc += x.x * ww.x + x.y * ww.y + x.z * ww.z + x.w * ww.w;
    }
#pragma unroll
    for (int off = 32; off; off >>= 1) acc += __shfl_xor(acc, off);
    if (lane == 0) ex[gid] = acc;
    return;
  }
  const int bid = blockIdx.x - 8192;
  if (bid < 256) {
    const int gid = bid * 256 + tid;  // 65536 groups of 8
    const int lane = gid & 63;
    const int kt = (gid >> 6) & 31;
    const int mt = gid >> 11;
    const int row = mt * 16 + (lane & 15);
    const int col = kt * 32 + (lane >> 4) * 8;
    const float* src = W_ih + row * Kn + col;
    uint4 ph;
    ph.x = pack2_f16(src[0], src[1]);
    ph.y = pack2_f16(src[2], src[3]);
    ph.z = pack2_f16(src[4], src[5]);
    ph.w = pack2_f16(src[6], src[7]);
    ((uint4*)whf)[gid] = ph;
  } else {
    const int g = (bid - 256) * 256 + tid;  // 0..8191
    const int l = g & 63;
    const int kf = (g >> 6) & 3;
    const int nt = g >> 8;                  // 0..31
    const int row = nt * 16 + (l & 15);     // gate row n
    const int col = kf * 32 + (l >> 4) * 8; // k
    const float* src = W_hh + (size_t)row * Hn + col;
    uint4 ph;
    ph.x = pack2_f16(src[0], src[1]);
    ph.y = pack2_f16(src[2], src[3]);
    ph.z = pack2_f16(src[4], src[5]);
    ph.w = pack2_f16(src[6], src[7]);
    ((uint4*)whh)[g] = ph;
  }
}

// ---------------------------------------------------------------------------
// K3: gates GEMM, f16 single-pass. R8: epilogue now writes TRANSPOSED
// gx[b][t][j] (t-major) so k_rec can read gates coalesced from L2 and skip
// its 128KB/block LDS preload. Same 34.8KB LDS bounce, pitch 136 (16B-align
// for b128 reads; b64 writes land ~2-4-way conflicts, acceptable).
// ---------------------------------------------------------------------------
__global__ __launch_bounds__(256, 2) void k_gates(
    const float* __restrict__ input, const float* __restrict__ ex,
    const unsigned short* __restrict__ whf,
    unsigned short* __restrict__ gx) {
  __shared__ __align__(16) unsigned char smem[34816];
  __shared__ float a_lds[Dn];
  __shared__ float sred[8];
  unsigned short* buf0 = (unsigned short*)smem;
  unsigned short* buf1 = buf0 + 8192;
  _Float16* lds_out = (_Float16*)smem;

  const int tid = threadIdx.x;
  const int bid = blockIdx.x;
  const int p = (bid >> 3) & 3;
  const int b = (bid & 7) | ((bid >> 5) << 3);
  const int w = tid >> 6;
  const int lane = tid & 63;
  const int quad = lane >> 4;
  const int l15 = lane & 15;

  // ---- in-block softmax over ex[b,:] -> a_lds ----
  float v = (tid < Dn) ? ex[b * Dn + tid] : -3.4e38f;
  float m = v;
#pragma unroll
  for (int off = 32; off; off >>= 1) m = fmaxf(m, __shfl_xor(m, off));
  if (lane == 0) sred[w] = m;
  __syncthreads();
  m = fmaxf(fmaxf(sred[0], sred[1]), fmaxf(sred[2], sred[3]));
  float e = (tid < Dn) ? __expf(v - m) : 0.f;
  float s = e;
#pragma unroll
  for (int off = 32; off; off >>= 1) s += __shfl_xor(s, off);
  if (lane == 0) sred[4 + w] = s;
  __syncthreads();
  s = sred[4] + sred[5] + sred[6] + sred[7];
  if (tid < Dn) a_lds[tid] = e / s;

  f32x4 acc[2][8];
#pragma unroll
  for (int i = 0; i < 2; ++i)
#pragma unroll
    for (int j = 0; j < 8; ++j) { f32x4 z = {0.f, 0.f, 0.f, 0.f}; acc[i][j] = z; }

  const float* xb = input + (size_t)b * Kn * Tn;
  const int mtg0 = p * 8 + w * 2;

  // W fragment register double-buffer: idx = mt*2 + kf
  h16x8 wcur[4], wnxt[4];
#pragma unroll
  for (int mt = 0; mt < 2; ++mt)
#pragma unroll
    for (int kf = 0; kf < 2; ++kf) {
      const size_t fo = (((size_t)(mtg0 + mt) * 32 + kf) * 64 + lane) * 8;
      wcur[mt * 2 + kf] = *(const h16x8*)(whf + fo);
    }

  __syncthreads();  // a_lds ready

  // ---- stage tile 0 ----
  float xr[2][2][8];
#pragma unroll
  for (int ck = 0; ck < 2; ++ck)
#pragma unroll
    for (int ct = 0; ct < 2; ++ct) {
      const int kb = 2 * w + ck;
      const float* col = xb + (size_t)(kb * 8) * Tn + lane + 64 * ct;
#pragma unroll
      for (int j = 0; j < 8; ++j) xr[ck][ct][j] = col[(size_t)j * Tn];
    }
#pragma unroll
  for (int ck = 0; ck < 2; ++ck) {
    const int kb = 2 * w + ck;
    const float av = a_lds[kb];
#pragma unroll
    for (int ct = 0; ct < 2; ++ct) {
      const int tt = lane + 64 * ct;
      uint4 pk;
      pk.x = pack2_f16(av * xr[ck][ct][0], av * xr[ck][ct][1]);
      pk.y = pack2_f16(av * xr[ck][ct][2], av * xr[ck][ct][3]);
      pk.z = pack2_f16(av * xr[ck][ct][4], av * xr[ck][ct][5]);
      pk.w = pack2_f16(av * xr[ck][ct][6], av * xr[ck][ct][7]);
      *(uint4*)(buf0 + (size_t)(kb * 128 + tt) * 8) = pk;
    }
  }
  __syncthreads();

  for (int kt = 0; kt < 16; ++kt) {
    unsigned short* cur = (kt & 1) ? buf1 : buf0;
    unsigned short* nxt = (kt & 1) ? buf0 : buf1;
    // ---- prefetch next x tile + next W frags (consumed after MFMA) ----
    if (kt < 15) {
      const int k0n = (kt + 1) * 64;
#pragma unroll
      for (int ck = 0; ck < 2; ++ck)
#pragma unroll
        for (int ct = 0; ct < 2; ++ct) {
          const int kb = 2 * w + ck;
          const float* col = xb + (size_t)(k0n + kb * 8) * Tn + lane + 64 * ct;
#pragma unroll
          for (int j = 0; j < 8; ++j) xr[ck][ct][j] = col[(size_t)j * Tn];
        }
#pragma unroll
      for (int mt = 0; mt < 2; ++mt)
#pragma unroll
        for (int kf = 0; kf < 2; ++kf) {
          const size_t fo = (((size_t)(mtg0 + mt) * 32 + (kt + 1) * 2 + kf) * 64 + lane) * 8;
          wnxt[mt * 2 + kf] = *(const h16x8*)(whf + fo);
        }
    }
    // ---- MFMA on current tile ----
#pragma unroll
    for (int kf = 0; kf < 2; ++kf) {
      h16x8 bfr[8];
      const int kbr = kf * 4 + quad;
#pragma unroll
      for (int nt = 0; nt < 8; ++nt)
        bfr[nt] = *(const h16x8*)(cur + (size_t)(kbr * 128 + nt * 16 + l15) * 8);
#pragma unroll
      for (int mt = 0; mt < 2; ++mt)
#pragma unroll
        for (int nt = 0; nt < 8; ++nt) {
          acc[mt][nt] = __builtin_amdgcn_mfma_f32_16x16x32_f16(wcur[mt * 2 + kf], bfr[nt], acc[mt][nt], 0, 0, 0);
        }
    }
    // ---- convert prefetched tile into other buffer; rotate W regs ----
    if (kt < 15) {
#pragma unroll
      for (int ck = 0; ck < 2; ++ck) {
        const int kb = 2 * w + ck;
        const float av = a_lds[(kt + 1) * 8 + kb];
#pragma unroll
        for (int ct = 0; ct < 2; ++ct) {
          const int tt = lane + 64 * ct;
          uint4 pk;
          pk.x = pack2_f16(av * xr[ck][ct][0], av * xr[ck][ct][1]);
          pk.y = pack2_f16(av * xr[ck][ct][2], av * xr[ck][ct][3]);
          pk.z = pack2_f16(av * xr[ck][ct][4], av * xr[ck][ct][5]);
          pk.w = pack2_f16(av * xr[ck][ct][6], av * xr[ck][ct][7]);
          *(uint4*)(nxt + (size_t)(kb * 128 + tt) * 8) = pk;
        }
      }
#pragma unroll
      for (int i = 0; i < 4; ++i) wcur[i] = wnxt[i];
    }
    __syncthreads();
  }

  // ---- epilogue: TRANSPOSED bounce -> gx[b][t][p*128 + j] (pitch 136) ----
  // acc[mt][nt][r] = C[j = (w*2+mt)*16 + quad*4 + r][t = nt*16 + l15]
#pragma unroll
  for (int mt = 0; mt < 2; ++mt)
#pragma unroll
    for (int nt = 0; nt < 8; ++nt) {
      const int jl = (w * 2 + mt) * 16 + quad * 4;
      const int tt = nt * 16 + l15;
      h16x4 v4;
      v4.x = (_Float16)acc[mt][nt][0];
      v4.y = (_Float16)acc[mt][nt][1];
      v4.z = (_Float16)acc[mt][nt][2];
      v4.w = (_Float16)acc[mt][nt][3];
      *(h16x4*)(lds_out + tt * 136 + jl) = v4;  // b64, 8B-aligned
    }
  __syncthreads();
  {
    const int tr = tid >> 1, half = tid & 1;  // tr = t row
    const uint4* lsrc = (const uint4*)(lds_out + tr * 136 + half * 64);
    uint4* gdst = (uint4*)(gx + (((size_t)b * Tn + tr) * Mn) + p * 128 + half * 64);
#pragma unroll
    for (int i = 0; i < 8; ++i) gdst[i] = lsrc[i];
  }
}

// ---------------------------------------------------------------------------
// K4: LSTM recurrence via MFMA. 256 blocks x 512 thr (8 waves, 2/SIMD).
// R8 restructure, from R7 counters (94us = 1766 cyc/step; MFMA issue only
// ~160 cyc -> latency-bound serial chain + 15us gxl preload):
//  - NO gx LDS preload: gates read from transposed gx[b][t][j] (L2/L3),
//    PREFETCHED one step ahead -> global latency off the critical path.
//  - wave w owns d in [16w,16w+16); its n-tiles {w,8+w,16+w,24+w} give all
//    4 gates of d at acc_q[0] of lane (l&15): A-rows all = h -> every C row
//    = gates -> NO shfl/exchange at all. 16 MFMA/wave (was 32), 2-deep chains.
//  - LDS = 512B h2l double-buffer only; one barrier/step.
// ---------------------------------------------------------------------------
__global__ __launch_bounds__(512) void k_rec(
    const unsigned short* __restrict__ gx, const unsigned short* __restrict__ whh,
    const float* __restrict__ b_ih, const float* __restrict__ b_hh,
    float* __restrict__ out) {
  __shared__ __align__(16) _Float16 h2l[2][Hn];  // double buffer

  const int tid = threadIdx.x;
  const int b = blockIdx.x;
  const int w = tid >> 6, l = tid & 63;
  const int d = w * 16 + (l & 15);   // output dim this lane serves

  float bs[4];
#pragma unroll
  for (int q = 0; q < 4; ++q) bs[q] = b_ih[q * 128 + d] + b_hh[q * 128 + d];

  // W_hh^T B-frags: gate q -> n-tile q*8+w; 4 k-frags (64 VGPRs total)
  h16x8 wf[4][4];
#pragma unroll
  for (int q = 0; q < 4; ++q) {
    const int nt = q * 8 + w;
#pragma unroll
    for (int kf = 0; kf < 4; ++kf) {
      const size_t fo = (((size_t)nt * 4 + kf) * 64 + l) * 8;
      wf[q][kf] = *(const h16x8*)(whh + fo);
    }
  }
  if (tid < Hn) h2l[0][tid] = (_Float16)0.f;
  float c_st = 0.f;

  const unsigned short* gb = gx + (size_t)b * Tn * Mn;
  unsigned short gc0 = gb[0 * 128 + d];
  unsigned short gc1 = gb[1 * 128 + d];
  unsigned short gc2 = gb[2 * 128 + d];
  unsigned short gc3 = gb[3 * 128 + d];
  __syncthreads();

  float* outp = out + (size_t)b * Tn * Hn;
  const int aoff = (l >> 4) * 8;  // k-slice this lane supplies to A-frags
  for (int t = 0; t < Tn; ++t) {
    // prefetch next step's gate inputs (independent of h -> fully hidden)
    const int tn = (t < Tn - 1) ? t + 1 : t;
    const unsigned short* gr = gb + (size_t)tn * Mn;
    const unsigned short gn0 = gr[0 * 128 + d];
    const unsigned short gn1 = gr[1 * 128 + d];
    const unsigned short gn2 = gr[2 * 128 + d];
    const unsigned short gn3 = gr[3 * 128 + d];
    // A-frags: h broadcast (4-address b128 reads, conflict-free)
    const _Float16* hb = &h2l[t & 1][0];
    const h16x8 af0 = *(const h16x8*)(hb + 0 + aoff);
    const h16x8 af1 = *(const h16x8*)(hb + 32 + aoff);
    const h16x8 af2 = *(const h16x8*)(hb + 64 + aoff);
    const h16x8 af3 = *(const h16x8*)(hb + 96 + aoff);
    const f32x4 zzero = {0.f, 0.f, 0.f, 0.f};
    float gt[4];
#pragma unroll
    for (int q = 0; q < 4; ++q) {
      f32x4 za = __builtin_amdgcn_mfma_f32_16x16x32_f16(af0, wf[q][0], zzero, 0, 0, 0);
      za = __builtin_amdgcn_mfma_f32_16x16x32_f16(af1, wf[q][1], za, 0, 0, 0);
      f32x4 zb = __builtin_amdgcn_mfma_f32_16x16x32_f16(af2, wf[q][2], zzero, 0, 0, 0);
      zb = __builtin_amdgcn_mfma_f32_16x16x32_f16(af3, wf[q][3], zb, 0, 0, 0);
      gt[q] = za[0] + zb[0];
    }
    const float gi = gt[0] + bs[0] + (float)(*(const _Float16*)&gc0);
    const float gf = gt[1] + bs[1] + (float)(*(const _Float16*)&gc1);
    const float gg = gt[2] + bs[2] + (float)(*(const _Float16*)&gc2);
    const float go = gt[3] + bs[3] + (float)(*(const _Float16*)&gc3);
    c_st = sigm(gf) * c_st + sigm(gi) * tanh_fast(gg);
    const float hnew = sigm(go) * tanh_fast(c_st);
    if (l < 16) {
      outp[t * Hn + d] = hnew;
      h2l[(t + 1) & 1][d] = (_Float16)hnew;
    }
    gc0 = gn0; gc1 = gn1; gc2 = gn2; gc3 = gn3;
    __syncthreads();  // h2l[nxt] writes -> next-step A-frag reads
  }
}

// ---------------------------------------------------------------------------
extern "C" void kernel_launch(void* const* d_in, const int* in_sizes, int n_in,
                              void* d_out, int out_size, void* d_ws, size_t ws_size,
                              hipStream_t stream) {
  (void)in_sizes; (void)n_in; (void)out_size; (void)ws_size;
  const float* input = (const float*)d_in[0];
  const float* w_attn = (const float*)d_in[1];
  // d_in[2] = b_attn: dead (softmax shift-invariance), as are w_h, w_c.
  const float* W_ih = (const float*)d_in[3];
  const float* W_hh = (const float*)d_in[4];
  const float* b_ih = (const float*)d_in[5];
  const float* b_hh = (const float*)d_in[6];
  float* out = (float*)d_out;

  char* ws = (char*)d_ws;
  float* ex = (float*)ws;                                   // 131072 B
  unsigned short* whf = (unsigned short*)(ws + 131072);      // 1 MB (f16 W_ih frags)
  unsigned short* whh = (unsigned short*)(ws + 1179648);     // 131072 B (W_hh^T B-frags)
  unsigned short* gxw = (unsigned short*)(ws + 1310720);     // 33.5 MB (t-major gates)

  k_ex_prep<<<8480, 256, 0, stream>>>(input, w_attn, W_ih, W_hh, ex, whf, whh);
  k_gates<<<1024, 256, 0, stream>>>(input, ex, whf, gxw);
  k_rec<<<Bn, 512, 0, stream>>>(gxw, whh, b_ih, b_hh, out);
}